// Round 3
// baseline (243.126 us; speedup 1.0000x reference)
//
#include <hip/hip_runtime.h>

// out = x * diag (broadcast over last axis). x: 32768 x 4096 f32, diag: 4096 f32.
// Memory-bound streaming kernel:
//  - f32x4 (native clang vector; 16B/lane) accesses — nontemporal builtins
//    require native vector types, not HIP_vector_type.
//  - grid stride (2048 x 256 = 524288) is a multiple of CH4=1024, so each
//    thread's channel group is FIXED -> diag load hoisted out of the loop.
//  - unroll x4 with independent loads for memory-level parallelism.
//  - nontemporal loads/stores: 1 GB streaming footprint > all caches.

#define CH4 1024   // 4096 channels / 4 floats per float4

typedef float f32x4 __attribute__((ext_vector_type(4)));

template <bool HOIST>
__global__ __launch_bounds__(256)
void DiagonalLinear_80960133529733_kernel(const f32x4* __restrict__ x,
                                          const f32x4* __restrict__ diag,
                                          f32x4* __restrict__ out,
                                          long long n4) {
    const long long stride = (long long)gridDim.x * blockDim.x;
    long long i = (long long)blockIdx.x * blockDim.x + threadIdx.x;

    f32x4 dv;
    if (HOIST) dv = diag[i & (CH4 - 1)];   // channel group constant per thread

    // Main unrolled loop: 4 independent load/mul/store streams.
    for (; i + 3 * stride < n4; i += 4 * stride) {
        f32x4 a = __builtin_nontemporal_load(&x[i]);
        f32x4 b = __builtin_nontemporal_load(&x[i + stride]);
        f32x4 c = __builtin_nontemporal_load(&x[i + 2 * stride]);
        f32x4 d = __builtin_nontemporal_load(&x[i + 3 * stride]);
        if (!HOIST) dv = diag[i & (CH4 - 1)];
        a *= dv;
        b *= dv;
        c *= dv;
        d *= dv;
        __builtin_nontemporal_store(a, &out[i]);
        __builtin_nontemporal_store(b, &out[i + stride]);
        __builtin_nontemporal_store(c, &out[i + 2 * stride]);
        __builtin_nontemporal_store(d, &out[i + 3 * stride]);
    }
    // Tail
    for (; i < n4; i += stride) {
        f32x4 xv = __builtin_nontemporal_load(&x[i]);
        f32x4 dvv = HOIST ? dv : diag[i & (CH4 - 1)];
        __builtin_nontemporal_store(xv * dvv, &out[i]);
    }
}

extern "C" void kernel_launch(void* const* d_in, const int* in_sizes, int n_in,
                              void* d_out, int out_size, void* d_ws, size_t ws_size,
                              hipStream_t stream) {
    const float* x    = (const float*)d_in[0];
    const float* diag = (const float*)d_in[1];
    float* out        = (float*)d_out;

    const long long n  = (long long)in_sizes[0];   // 32768*4096
    const long long n4 = n / 4;                    // 4096 % 4 == 0

    const int block = 256;
    long long want = (n4 + block - 1) / block;
    int grid = (int)(want < 2048 ? want : 2048);

    const long long stride = (long long)grid * block;
    if ((stride & (CH4 - 1)) == 0) {
        // stride multiple of 1024 float4 -> channel group fixed per thread
        DiagonalLinear_80960133529733_kernel<true><<<grid, block, 0, stream>>>(
            (const f32x4*)x, (const f32x4*)diag, (f32x4*)out, n4);
    } else {
        DiagonalLinear_80960133529733_kernel<false><<<grid, block, 0, stream>>>(
            (const f32x4*)x, (const f32x4*)diag, (f32x4*)out, n4);
    }
}

// Round 4
// 217.804 us; speedup vs baseline: 1.1163x; 1.1163x over previous
//
#include <hip/hip_runtime.h>

// out = x * diag (broadcast over last axis). x: 32768 x 4096 f32, diag: 4096 f32.
// Memory-bound streaming kernel. R4: revert nontemporal (regressed in R3);
// keep hoisted diag + 32-bit indexing + compiler unroll.
//  - f32x4 (16B/lane) accesses.
//  - grid stride (2048 x 256 = 524288) is a multiple of CH4=1024, so each
//    thread's channel group is FIXED -> diag load hoisted out of the loop.
//  - 32-bit indices: n4 = 2^25, byte offsets <= 2^29 fit u32 -> less addr VALU.

#define CH4 1024   // 4096 channels / 4 floats per float4

typedef float f32x4 __attribute__((ext_vector_type(4)));

template <bool HOIST>
__global__ __launch_bounds__(256)
void DiagonalLinear_80960133529733_kernel(const f32x4* __restrict__ x,
                                          const f32x4* __restrict__ diag,
                                          f32x4* __restrict__ out,
                                          unsigned int n4) {
    const unsigned int stride = gridDim.x * blockDim.x;
    unsigned int i = blockIdx.x * blockDim.x + threadIdx.x;

    f32x4 dv;
    if (HOIST) dv = diag[i & (CH4 - 1)];   // channel group constant per thread

#pragma unroll 4
    for (; i < n4; i += stride) {
        f32x4 xv = x[i];
        f32x4 dvv = HOIST ? dv : diag[i & (CH4 - 1)];
        out[i] = xv * dvv;
    }
}

extern "C" void kernel_launch(void* const* d_in, const int* in_sizes, int n_in,
                              void* d_out, int out_size, void* d_ws, size_t ws_size,
                              hipStream_t stream) {
    const float* x    = (const float*)d_in[0];
    const float* diag = (const float*)d_in[1];
    float* out        = (float*)d_out;

    const long long n  = (long long)in_sizes[0];   // 32768*4096
    const unsigned int n4 = (unsigned int)(n / 4); // 2^25, fits u32

    const int block = 256;
    long long want = ((long long)n4 + block - 1) / block;
    int grid = (int)(want < 2048 ? want : 2048);

    const unsigned int stride = (unsigned int)grid * block;
    if ((stride & (CH4 - 1)) == 0) {
        DiagonalLinear_80960133529733_kernel<true><<<grid, block, 0, stream>>>(
            (const f32x4*)x, (const f32x4*)diag, (f32x4*)out, n4);
    } else {
        DiagonalLinear_80960133529733_kernel<false><<<grid, block, 0, stream>>>(
            (const f32x4*)x, (const f32x4*)diag, (f32x4*)out, n4);
    }
}